// Round 1
// baseline (253.251 us; speedup 1.0000x reference)
//
#include <hip/hip_runtime.h>
#include <math.h>

#define NDIM   32
#define NPAIRS 528        // 32*33/2
#define NTRIP  5984       // C(34,3)
#define NCOLS  (1 + NDIM + NPAIRS + NTRIP + NDIM)   // 6577
#define ONE_IDX 64        // index of the constant 1.0 in the per-row LDS array

// Packed index table: each column c of the library is
//   w[i] * w[j] * w[k]  with  w = [ z[0..31], sin(z)[0..31], 1.0f ]
// and (i, j, k) packed as three 7-bit fields of a u32.
struct Tbl { unsigned int v[NCOLS]; };

constexpr Tbl make_tbl() {
    Tbl t{};
    int c = 0;
    const unsigned ONE = ONE_IDX;
    // ones
    t.v[c++] = ONE | (ONE << 7) | (ONE << 14);
    // z
    for (unsigned i = 0; i < NDIM; ++i)
        t.v[c++] = i | (ONE << 7) | (ONE << 14);
    // pairs: np.triu_indices order (i ascending, j from i..31)
    for (unsigned i = 0; i < NDIM; ++i)
        for (unsigned j = i; j < NDIM; ++j)
            t.v[c++] = i | (j << 7) | (ONE << 14);
    // triples: a<=b<=c, a-major order
    for (unsigned a = 0; a < NDIM; ++a)
        for (unsigned b = a; b < NDIM; ++b)
            for (unsigned k = b; k < NDIM; ++k)
                t.v[c++] = a | (b << 7) | (k << 14);
    // sin(z)
    for (unsigned i = 0; i < NDIM; ++i)
        t.v[c++] = (NDIM + i) | (ONE << 7) | (ONE << 14);
    return t;
}

__device__ __constant__ Tbl TBL = make_tbl();

__global__ __launch_bounds__(256)
void sindy_library_kernel(const float* __restrict__ z, float* __restrict__ out) {
    __shared__ float w[ONE_IDX + 1];
    const int row = blockIdx.x;
    const int tid = threadIdx.x;

    if (tid < NDIM) {
        float v = z[row * NDIM + tid];
        w[tid]        = v;
        w[NDIM + tid] = sinf(v);
    }
    if (tid == 255) w[ONE_IDX] = 1.0f;
    __syncthreads();

    const long long base = (long long)row * NCOLS;
    // 26 strided iterations; consecutive lanes -> consecutive addresses (coalesced).
    for (int c = tid; c < NCOLS; c += 256) {
        const unsigned e = TBL.v[c];
        const float v = w[e & 127] * w[(e >> 7) & 127] * w[(e >> 14) & 127];
        __builtin_nontemporal_store(v, &out[base + c]);
    }
}

extern "C" void kernel_launch(void* const* d_in, const int* in_sizes, int n_in,
                              void* d_out, int out_size, void* d_ws, size_t ws_size,
                              hipStream_t stream) {
    const float* z = (const float*)d_in[0];
    float* out     = (float*)d_out;
    const int rows = in_sizes[0] / NDIM;   // 8192
    sindy_library_kernel<<<rows, 256, 0, stream>>>(z, out);
}